// Round 7
// baseline (653.322 us; speedup 1.0000x reference)
//
#include <hip/hip_runtime.h>
#include <math.h>

#define N_NODES 50000
#define N_EDGES 300000
#define IN_DIM 64
#define H 256
#define LAYERS 4
#define NB 181
#define NGRAPH 64
#define EE (N_EDGES + N_NODES)
#define NEG_SLOPE 0.2f
#define LN_EPS 1e-5f

typedef unsigned short u16;
typedef __attribute__((ext_vector_type(8))) _Float16 half8;
typedef __attribute__((ext_vector_type(2))) _Float16 half2v;
typedef __attribute__((ext_vector_type(4))) float floatx4;

__device__ __forceinline__ u16 f2h(float f) {
  _Float16 h = (_Float16)f;
  return __builtin_bit_cast(u16, h);
}
__device__ __forceinline__ float h2f(u16 b) {
  return (float)__builtin_bit_cast(_Float16, b);
}

__device__ __forceinline__ float wave_reduce_sum(float v) {
  #pragma unroll
  for (int off = 32; off > 0; off >>= 1) v += __shfl_xor(v, off, 64);
  return v;
}

// ---------------- casts ----------------
__global__ void cast_f16_kernel(const float* __restrict__ in, u16* __restrict__ out, int n4) {
  int i = blockIdx.x * 256 + threadIdx.x;
  if (i < n4) {
    float4 f = ((const float4*)in)[i];
    ushort4 o;
    o.x = f2h(f.x); o.y = f2h(f.y); o.z = f2h(f.z); o.w = f2h(f.w);
    ((ushort4*)out)[i] = o;
  }
}

__global__ void cast_weights_kernel(
    const float* __restrict__ W_in, const float* __restrict__ Wg1,
    const float* __restrict__ Wl, const float* __restrict__ Wr,
    u16* __restrict__ win_h, u16* __restrict__ wg1_h,
    u16* __restrict__ wl_h, u16* __restrict__ wr_h)
{
  int i = blockIdx.x * 256 + threadIdx.x;
  int which = blockIdx.y;
  const float* s; u16* dd; int n4;
  if (which == 0)      { s = W_in; dd = win_h; n4 = H * IN_DIM / 4; }
  else if (which == 1) { s = Wg1;  dd = wg1_h; n4 = H * H / 4; }
  else if (which == 2) { s = Wl;   dd = wl_h;  n4 = LAYERS * H * H / 4; }
  else                 { s = Wr;   dd = wr_h;  n4 = LAYERS * H * H / 4; }
  if (i < n4) {
    float4 f = ((const float4*)s)[i];
    ushort4 o;
    o.x = f2h(f.x); o.y = f2h(f.y); o.z = f2h(f.z); o.w = f2h(f.w);
    ((ushort4*)dd)[i] = o;
  }
}

// ---------------- CSR build ----------------
__global__ void init_counts_kernel(int* __restrict__ cnt) {
  int i = blockIdx.x * 256 + threadIdx.x;
  if (i < N_NODES) cnt[i] = 1;  // self loop
}

__global__ void count_edges_kernel(const int* __restrict__ dst, int* __restrict__ cnt) {
  int e = blockIdx.x * 256 + threadIdx.x;
  if (e < N_EDGES) atomicAdd(&cnt[dst[e]], 1);
}

__global__ void scan_blocks_kernel(const int* __restrict__ cnt, int* __restrict__ partial,
                                   int* __restrict__ bsums, int n) {
  __shared__ int buf[256];
  int tid = threadIdx.x;
  int i = blockIdx.x * 256 + tid;
  buf[tid] = (i < n) ? cnt[i] : 0;
  __syncthreads();
  #pragma unroll
  for (int off = 1; off < 256; off <<= 1) {
    int t = (tid >= off) ? buf[tid - off] : 0;
    __syncthreads();
    buf[tid] += t;
    __syncthreads();
  }
  if (i < n) partial[i] = buf[tid];
  if (tid == 255) bsums[blockIdx.x] = buf[255];
}

__global__ void scan_sums_kernel(int* __restrict__ bsums, int nblk) {
  __shared__ int buf[256];
  int tid = threadIdx.x;
  buf[tid] = (tid < nblk) ? bsums[tid] : 0;
  __syncthreads();
  #pragma unroll
  for (int off = 1; off < 256; off <<= 1) {
    int t = (tid >= off) ? buf[tid - off] : 0;
    __syncthreads();
    buf[tid] += t;
    __syncthreads();
  }
  if (tid < nblk) bsums[tid] = buf[tid];
}

__global__ void scan_write_kernel(const int* __restrict__ partial, const int* __restrict__ bsums,
                                  int* __restrict__ rowp, int n) {
  int i = blockIdx.x * 256 + threadIdx.x;
  if (i < n) {
    int b = blockIdx.x;
    int off = (b > 0) ? bsums[b - 1] : 0;
    rowp[i + 1] = partial[i] + off;
    if (i == 0) rowp[0] = 0;
  }
}

__global__ void fill_self_kernel(const int* __restrict__ rowp, int* __restrict__ col,
                                 int* __restrict__ fillpos) {
  int i = blockIdx.x * 256 + threadIdx.x;
  if (i < N_NODES) {
    int p = rowp[i];
    col[p] = i;
    fillpos[i] = p + 1;
  }
}

__global__ void fill_edges_kernel(const int* __restrict__ src, const int* __restrict__ dst,
                                  int* __restrict__ fillpos, int* __restrict__ col) {
  int e = blockIdx.x * 256 + threadIdx.x;
  if (e < N_EDGES) {
    int d = dst[e];
    int p = atomicAdd(&fillpos[d], 1);
    col[p] = src[e];
  }
}

// ---------------- MFMA GEMM tiles ----------------
#define GTM 128
#define GTK 64
#define LDB 72
#define SSTR 132

// input projection: out_h[M,256] = A[M,K]@W^T + bias (fp16 out, staged coalesced)
__global__ __launch_bounds__(256) void gemm_proj_kernel(
    const u16* __restrict__ A, const u16* __restrict__ W,
    const float* __restrict__ bias, u16* __restrict__ outh, int M, int K)
{
  __shared__ u16 smem[2 * GTM * LDB];
  u16* As = smem;
  u16* Bs = smem + GTM * LDB;
  int tid = threadIdx.x;
  int lane = tid & 63;
  int wave = tid >> 6;
  int wm = (wave >> 1) * 64;
  int wn = (wave & 1) * 64;
  int bm = blockIdx.y * GTM;
  int n0 = blockIdx.x * 128;
  int lr = tid >> 3;
  int lc = (tid & 7) * 8;

  floatx4 zero4 = {0.f, 0.f, 0.f, 0.f};
  floatx4 acc[4][4];
  #pragma unroll
  for (int i = 0; i < 4; i++)
    #pragma unroll
    for (int j = 0; j < 4; j++) acc[i][j] = zero4;

  int q8 = (lane >> 4) * 8;
  int mrow = lane & 15;

  for (int k0 = 0; k0 < K; k0 += GTK) {
    __syncthreads();
    #pragma unroll
    for (int p = 0; p < 4; p++) {
      int row = lr + p * 32;
      int gr = bm + row;
      uint4 av = {0, 0, 0, 0};
      if (gr < M) av = *(const uint4*)&A[(size_t)gr * K + k0 + lc];
      *(uint4*)&As[row * LDB + lc] = av;
      uint4 bv = *(const uint4*)&W[(size_t)(n0 + row) * K + k0 + lc];
      *(uint4*)&Bs[row * LDB + lc] = bv;
    }
    __syncthreads();
    #pragma unroll
    for (int h = 0; h < 2; h++) {
      half8 af[4], bf[4];
      #pragma unroll
      for (int i = 0; i < 4; i++)
        af[i] = *(const half8*)&As[(wm + i * 16 + mrow) * LDB + h * 32 + q8];
      #pragma unroll
      for (int j = 0; j < 4; j++)
        bf[j] = *(const half8*)&Bs[(wn + j * 16 + mrow) * LDB + h * 32 + q8];
      #pragma unroll
      for (int i = 0; i < 4; i++)
        #pragma unroll
        for (int j = 0; j < 4; j++)
          acc[i][j] = __builtin_amdgcn_mfma_f32_16x16x32_f16(af[i], bf[j], acc[i][j], 0, 0, 0);
    }
  }

  __syncthreads();
  u16* stage = smem;
  int ccol = lane & 15;
  int crow4 = (lane >> 4) * 4;
  #pragma unroll
  for (int j = 0; j < 4; j++) {
    float bv = bias[n0 + wn + j * 16 + ccol];
    #pragma unroll
    for (int i = 0; i < 4; i++) {
      #pragma unroll
      for (int r = 0; r < 4; r++) {
        int row = wm + i * 16 + crow4 + r;
        stage[row * SSTR + wn + j * 16 + ccol] = f2h(acc[i][j][r] + bv);
      }
    }
  }
  __syncthreads();
  int rr = tid >> 1;
  int c0 = (tid & 1) * 64;
  int grow = bm + rr;
  if (grow < M) {
    const ushort4* sp = (const ushort4*)&stage[rr * SSTR + c0];
    ushort4* gp = (ushort4*)&outh[(size_t)grow * H + n0 + c0];
    #pragma unroll
    for (int q = 0; q < 16; q++) gp[q] = sp[q];
  }
}

// ---------------- dual GEMM v2: A-resident in LDS, 64-row m-tiles ----------------
#define DTM 64
#define AST 264
#define SSTR2 132

__global__ __launch_bounds__(256) void gemm_dual2_kernel(
    const u16* __restrict__ A, const u16* __restrict__ Wlb, const u16* __restrict__ Wrb,
    const float* __restrict__ biasL, const float* __restrict__ biasR,
    u16* __restrict__ outL, u16* __restrict__ outR, int M)
{
  __shared__ u16 As[DTM * AST];
  __shared__ u16 Bs[128 * LDB];
  int tid = threadIdx.x;
  int lane = tid & 63;
  int wave = tid >> 6;
  int wn = wave * 32;
  int bm = blockIdx.x * DTM;
  int mrow = lane & 15;
  int q8 = (lane >> 4) * 8;
  int ccol = lane & 15;
  int crow4 = (lane >> 4) * 4;

  {
    int col = (tid & 31) * 8;
    int r0 = tid >> 5;
    #pragma unroll
    for (int it = 0; it < 8; it++) {
      int row = r0 + it * 8;
      int gr = bm + row;
      uint4 av = {0, 0, 0, 0};
      if (gr < M) av = *(const uint4*)&A[(size_t)gr * H + col];
      *(uint4*)&As[row * AST + col] = av;
    }
  }

  floatx4 zero4 = {0.f, 0.f, 0.f, 0.f};

  for (int nt = 0; nt < 4; nt++) {
    const u16* W = (nt < 2) ? Wlb : Wrb;
    const float* bias = (nt < 2) ? biasL : biasR;
    u16* outp = (nt < 2) ? outL : outR;
    int n0 = (nt & 1) * 128;

    floatx4 acc[4][2];
    #pragma unroll
    for (int i = 0; i < 4; i++) {
      acc[i][0] = zero4;
      acc[i][1] = zero4;
    }

    for (int k0 = 0; k0 < H; k0 += 64) {
      __syncthreads();
      {
        int col = (tid & 7) * 8;
        int r0 = tid >> 3;
        #pragma unroll
        for (int p2 = 0; p2 < 4; p2++) {
          int row = r0 + p2 * 32;
          uint4 bv = *(const uint4*)&W[(size_t)(n0 + row) * H + k0 + col];
          *(uint4*)&Bs[row * LDB + col] = bv;
        }
      }
      __syncthreads();
      #pragma unroll
      for (int h = 0; h < 2; h++) {
        half8 af[4], bf[2];
        #pragma unroll
        for (int i = 0; i < 4; i++)
          af[i] = *(const half8*)&As[(i * 16 + mrow) * AST + k0 + h * 32 + q8];
        #pragma unroll
        for (int j = 0; j < 2; j++)
          bf[j] = *(const half8*)&Bs[(wn + j * 16 + mrow) * LDB + h * 32 + q8];
        #pragma unroll
        for (int i = 0; i < 4; i++)
          #pragma unroll
          for (int j = 0; j < 2; j++)
            acc[i][j] = __builtin_amdgcn_mfma_f32_16x16x32_f16(af[i], bf[j], acc[i][j], 0, 0, 0);
      }
    }

    __syncthreads();
    u16* stage = Bs;
    #pragma unroll
    for (int j = 0; j < 2; j++) {
      float bv = bias[n0 + wn + j * 16 + ccol];
      #pragma unroll
      for (int i = 0; i < 4; i++) {
        #pragma unroll
        for (int r = 0; r < 4; r++) {
          int row = i * 16 + crow4 + r;
          stage[row * SSTR2 + wn + j * 16 + ccol] = f2h(acc[i][j][r] + bv);
        }
      }
    }
    __syncthreads();
    {
      int row = tid >> 2;
      int c0 = (tid & 3) * 32;
      int grow = bm + row;
      if (grow < M) {
        #pragma unroll
        for (int q = 0; q < 8; q++)
          *(ushort4*)&outp[(size_t)grow * H + n0 + c0 + q * 4] =
              *(const ushort4*)&stage[row * SSTR2 + c0 + q * 4];
      }
    }
  }
}

// gate GEMM: gate[row] += sum_col relu(x@Wg1 + bg1)[col] * Wg2[col]; gate pre-init to bg2
__global__ __launch_bounds__(256) void gemm_gate_kernel(
    const u16* __restrict__ A, const u16* __restrict__ W,
    const float* __restrict__ bias, const float* __restrict__ Wg2,
    float* __restrict__ gate, int M)
{
  __shared__ u16 smem[2 * GTM * LDB];
  u16* As = smem;
  u16* Bs = smem + GTM * LDB;
  int tid = threadIdx.x;
  int lane = tid & 63;
  int wave = tid >> 6;
  int wm = (wave >> 1) * 64;
  int wn = (wave & 1) * 64;
  int bm = blockIdx.y * GTM;
  int bn = blockIdx.x * 128;
  int lr = tid >> 3;
  int lc = (tid & 7) * 8;

  floatx4 zero4 = {0.f, 0.f, 0.f, 0.f};
  floatx4 acc[4][4];
  #pragma unroll
  for (int i = 0; i < 4; i++)
    #pragma unroll
    for (int j = 0; j < 4; j++) acc[i][j] = zero4;

  int q8 = (lane >> 4) * 8;
  int mrow = lane & 15;

  for (int k0 = 0; k0 < H; k0 += GTK) {
    __syncthreads();
    #pragma unroll
    for (int p = 0; p < 4; p++) {
      int row = lr + p * 32;
      int gr = bm + row;
      uint4 av = {0, 0, 0, 0};
      if (gr < M) av = *(const uint4*)&A[(size_t)gr * H + k0 + lc];
      *(uint4*)&As[row * LDB + lc] = av;
      uint4 bv = *(const uint4*)&W[(size_t)(bn + row) * H + k0 + lc];
      *(uint4*)&Bs[row * LDB + lc] = bv;
    }
    __syncthreads();
    #pragma unroll
    for (int h = 0; h < 2; h++) {
      half8 af[4], bf[4];
      #pragma unroll
      for (int i = 0; i < 4; i++)
        af[i] = *(const half8*)&As[(wm + i * 16 + mrow) * LDB + h * 32 + q8];
      #pragma unroll
      for (int j = 0; j < 4; j++)
        bf[j] = *(const half8*)&Bs[(wn + j * 16 + mrow) * LDB + h * 32 + q8];
      #pragma unroll
      for (int i = 0; i < 4; i++)
        #pragma unroll
        for (int j = 0; j < 4; j++)
          acc[i][j] = __builtin_amdgcn_mfma_f32_16x16x32_f16(af[i], bf[j], acc[i][j], 0, 0, 0);
    }
  }

  int ccol = lane & 15;
  float bv[4], wv[4];
  #pragma unroll
  for (int j = 0; j < 4; j++) {
    int col = bn + wn + j * 16 + ccol;
    bv[j] = bias[col];
    wv[j] = Wg2[col];
  }
  #pragma unroll
  for (int i = 0; i < 4; i++) {
    #pragma unroll
    for (int r = 0; r < 4; r++) {
      float p = 0.f;
      #pragma unroll
      for (int j = 0; j < 4; j++) {
        float hcol = fmaxf(acc[i][j][r] + bv[j], 0.f);
        p += hcol * wv[j];
      }
      p += __shfl_xor(p, 1, 64);
      p += __shfl_xor(p, 2, 64);
      p += __shfl_xor(p, 4, 64);
      p += __shfl_xor(p, 8, 64);
      int row = bm + wm + i * 16 + (lane >> 4) * 4 + r;
      if ((lane & 15) == 0 && row < M) atomicAdd(&gate[row], p);
    }
  }
}

// ---------------- fused edge softmax + aggregate + LN + residual ----------------
// 2 edge slots x 32 lanes x 8 features; fp16 packed math; fp32 accumulators.
__global__ __launch_bounds__(256) void layer_fused_kernel(
    const u16* __restrict__ xl, const u16* __restrict__ xr,
    u16* __restrict__ xst,
    const int* __restrict__ rowp, const int* __restrict__ col,
    const float* __restrict__ att, const float* __restrict__ bias_c,
    const float* __restrict__ ln_g, const float* __restrict__ ln_b)
{
  int lane = threadIdx.x & 63;
  int v = blockIdx.x * 4 + (threadIdx.x >> 6);
  if (v >= N_NODES) return;
  int slot = lane >> 5;       // edge slot 0/1
  int fl = lane & 31;         // feature lane
  int f8 = fl << 3;           // 8 features per lane
  size_t rowbase = (size_t)v * H;

  // per-node preloads
  uint4 xrq = *(const uint4*)&xr[rowbase + f8];
  half2v xrh[4] = {
    __builtin_bit_cast(half2v, xrq.x), __builtin_bit_cast(half2v, xrq.y),
    __builtin_bit_cast(half2v, xrq.z), __builtin_bit_cast(half2v, xrq.w)};
  float4 attA = *(const float4*)&att[f8];
  float4 attB = *(const float4*)&att[f8 + 4];
  half2v ath[4] = {
    {(_Float16)attA.x, (_Float16)attA.y}, {(_Float16)attA.z, (_Float16)attA.w},
    {(_Float16)attB.x, (_Float16)attB.y}, {(_Float16)attB.z, (_Float16)attB.w}};
  const half2v kslope = {(_Float16)NEG_SLOPE, (_Float16)NEG_SLOPE};

  int beg = rowp[v], end = rowp[v + 1];
  float m = -INFINITY, d = 0.f;
  float o[8] = {0.f, 0.f, 0.f, 0.f, 0.f, 0.f, 0.f, 0.f};

  for (int p = beg; p < end; p += 2) {
    int valid1 = (p + 1 < end);
    int u0 = col[p];
    int u1 = valid1 ? col[p + 1] : u0;
    int u = slot ? u1 : u0;
    uint4 aq = *(const uint4*)&xl[(size_t)u * H + f8];
    half2v ah[4] = {
      __builtin_bit_cast(half2v, aq.x), __builtin_bit_cast(half2v, aq.y),
      __builtin_bit_cast(half2v, aq.z), __builtin_bit_cast(half2v, aq.w)};
    float pe = 0.f;
    #pragma unroll
    for (int q = 0; q < 4; q++) {
      half2v h = ah[q] + xrh[q];
      half2v l = __builtin_elementwise_max(h, h * kslope);  // leaky_relu (slope<1)
#if __has_builtin(__builtin_amdgcn_fdot2)
      pe = __builtin_amdgcn_fdot2(l, ath[q], pe, false);
#else
      pe += (float)l[0] * (float)ath[q][0] + (float)l[1] * (float)ath[q][1];
#endif
    }
    // reduce within 32-lane slot (xor masks stay inside the half)
    #pragma unroll
    for (int off = 16; off > 0; off >>= 1) pe += __shfl_xor(pe, off, 64);
    if (slot && !valid1) pe = -INFINITY;
    float peO = __shfl_xor(pe, 32, 64);
    float mn = fmaxf(m, fmaxf(pe, peO));
    float sc = __expf(m - mn);   // exp(-inf)=0 on first iteration
    float w = __expf(pe - mn);   // 0 for invalid slot
    d = fmaf(d, sc, w);
    #pragma unroll
    for (int q = 0; q < 8; q++) {
      float af = (float)((q & 1) ? ah[q >> 1][1] : ah[q >> 1][0]);
      o[q] = fmaf(o[q], sc, w * af);
    }
    m = mn;
  }

  // combine the two edge slots
  d += __shfl_xor(d, 32, 64);
  #pragma unroll
  for (int q = 0; q < 8; q++) o[q] += __shfl_xor(o[q], 32, 64);

  float invd = 1.0f / d;
  float4 bcA = *(const float4*)&bias_c[f8];
  float4 bcB = *(const float4*)&bias_c[f8 + 4];
  float bc[8] = {bcA.x, bcA.y, bcA.z, bcA.w, bcB.x, bcB.y, bcB.z, bcB.w};
  float ox[8];
  float part = 0.f;
  #pragma unroll
  for (int q = 0; q < 8; q++) {
    ox[q] = fmaf(o[q], invd, bc[q]);
    part += ox[q];
  }
  // LN mean/var: features live in 32 lanes (duplicated across halves) -> 5-step reduce
  #pragma unroll
  for (int off = 16; off > 0; off >>= 1) part += __shfl_xor(part, off, 64);
  float mean = part * (1.0f / H);
  float sq = 0.f;
  #pragma unroll
  for (int q = 0; q < 8; q++) {
    ox[q] -= mean;
    sq = fmaf(ox[q], ox[q], sq);
  }
  #pragma unroll
  for (int off = 16; off > 0; off >>= 1) sq += __shfl_xor(sq, off, 64);
  float rstd = rsqrtf(sq * (1.0f / H) + LN_EPS);

  if (slot == 0) {
    float4 gA = *(const float4*)&ln_g[f8];
    float4 gB = *(const float4*)&ln_g[f8 + 4];
    float4 bA = *(const float4*)&ln_b[f8];
    float4 bB = *(const float4*)&ln_b[f8 + 4];
    float gg[8] = {gA.x, gA.y, gA.z, gA.w, gB.x, gB.y, gB.z, gB.w};
    float bb[8] = {bA.x, bA.y, bA.z, bA.w, bB.x, bB.y, bB.z, bB.w};
    uint4 resq = *(const uint4*)&xst[rowbase + f8];
    half2v rh[4] = {
      __builtin_bit_cast(half2v, resq.x), __builtin_bit_cast(half2v, resq.y),
      __builtin_bit_cast(half2v, resq.z), __builtin_bit_cast(half2v, resq.w)};
    u16 yout[8];
    #pragma unroll
    for (int q = 0; q < 8; q++) {
      float res = (float)((q & 1) ? rh[q >> 1][1] : rh[q >> 1][0]);
      float y = fmaxf(fmaf(ox[q] * rstd, gg[q], bb[q]), 0.f) + res;
      yout[q] = f2h(y);
    }
    *(uint4*)&xst[rowbase + f8] = *(const uint4*)yout;
  }
}

// ---------------- gate init (+ graph-bounds defaults) ----------------
__global__ void gate_init_kernel(float* __restrict__ gate, const float* __restrict__ bg2,
                                 int* __restrict__ gstart, int* __restrict__ gend) {
  int i = blockIdx.x * 256 + threadIdx.x;
  if (i < N_NODES) gate[i] = bg2[0];
  if (i < NGRAPH) { gstart[i] = 0; gend[i] = 0; }
}

// ---------------- graph bounds (sorted batch) ----------------
__global__ void gbounds_kernel(const int* __restrict__ batch, int* __restrict__ gstart,
                               int* __restrict__ gend) {
  int i = blockIdx.x * 256 + threadIdx.x;
  if (i < N_NODES) {
    int b = batch[i];
    if (i == 0 || batch[i - 1] != b) gstart[b] = i;
    if (i == N_NODES - 1 || batch[i + 1] != b) gend[b] = i + 1;
  }
}

// ---------------- pooling: per-graph softmax stats (+ pooled zero) ----------------
__global__ __launch_bounds__(256) void pool_prep_kernel(
    const float* __restrict__ gate, const int* __restrict__ gstart,
    const int* __restrict__ gend, float* __restrict__ gmax, float* __restrict__ gdinv,
    float* __restrict__ pooled)
{
  __shared__ float red[256];
  int g = blockIdx.x, tid = threadIdx.x;
  pooled[(size_t)g * H + tid] = 0.f;
  int s = gstart[g], e = gend[g];
  float lm = -INFINITY;
  for (int i = s + tid; i < e; i += 256) lm = fmaxf(lm, gate[i]);
  red[tid] = lm;
  __syncthreads();
  for (int off = 128; off; off >>= 1) {
    if (tid < off) red[tid] = fmaxf(red[tid], red[tid + off]);
    __syncthreads();
  }
  float m = red[0];
  __syncthreads();
  float lsum = 0.0f;
  for (int i = s + tid; i < e; i += 256) lsum += __expf(gate[i] - m);
  red[tid] = lsum;
  __syncthreads();
  for (int off = 128; off; off >>= 1) {
    if (tid < off) red[tid] += red[tid + off];
    __syncthreads();
  }
  if (tid == 0) {
    gmax[g] = m;
    gdinv[g] = (s < e) ? 1.0f / red[0] : 0.0f;
  }
}

// ---------------- pooling: weighted accumulate (128 nodes per block, fp16 x) ----------------
__global__ __launch_bounds__(256) void pool_accum_kernel(
    const float* __restrict__ gate, const u16* __restrict__ xh,
    const int* __restrict__ batch, const float* __restrict__ gmax,
    const float* __restrict__ gdinv, float* __restrict__ pooled)
{
  __shared__ float wl[128];
  __shared__ int gl[128];
  int b0 = blockIdx.x * 128;
  int tid = threadIdx.x;
  if (tid < 128) {
    int v = b0 + tid;
    if (v < N_NODES) {
      int g = batch[v];
      gl[tid] = g;
      wl[tid] = __expf(gate[v] - gmax[g]) * gdinv[g];
    } else {
      gl[tid] = -1;
      wl[tid] = 0.f;
    }
  }
  __syncthreads();
  int cnt = min(128, N_NODES - b0);
  float acc = 0.f;
  int cur = gl[0];
  for (int j = 0; j < cnt; j++) {
    int g = gl[j];
    if (g != cur) {
      atomicAdd(&pooled[(size_t)cur * H + tid], acc);
      acc = 0.f;
      cur = g;
    }
    acc += wl[j] * h2f(xh[(size_t)(b0 + j) * H + tid]);
  }
  if (cur >= 0) atomicAdd(&pooled[(size_t)cur * H + tid], acc);
}

// ---------------- fused head: pooled -> z -> {cls, r1} -> residual ----------------
__global__ __launch_bounds__(256) void head_kernel(
    const float* __restrict__ pooled,
    const float* __restrict__ Ws, const float* __restrict__ bs,
    const float* __restrict__ Wc, const float* __restrict__ bc,
    const float* __restrict__ Wr1, const float* __restrict__ br1,
    const float* __restrict__ Wr2, const float* __restrict__ br2,
    float* __restrict__ out)
{
  __shared__ float psh[256];
  __shared__ float zsh[256];
  __shared__ float r1sh[128];
  int g = blockIdx.x, tid = threadIdx.x;
  psh[tid] = pooled[(size_t)g * H + tid];
  __syncthreads();
  {
    float acc = bs[tid];
    const float4* wr = (const float4*)&Ws[(size_t)tid * H];
    for (int k4 = 0; k4 < H / 4; k4++) {
      float4 wv = wr[k4];
      float4 av = *(const float4*)&psh[k4 * 4];
      acc += av.x * wv.x + av.y * wv.y + av.z * wv.z + av.w * wv.w;
    }
    zsh[tid] = fmaxf(acc, 0.f);
  }
  __syncthreads();
  if (tid < NB) {
    float acc = bc[tid];
    const float4* wr = (const float4*)&Wc[(size_t)tid * H];
    for (int k4 = 0; k4 < H / 4; k4++) {
      float4 wv = wr[k4];
      float4 av = *(const float4*)&zsh[k4 * 4];
      acc += av.x * wv.x + av.y * wv.y + av.z * wv.z + av.w * wv.w;
    }
    out[(size_t)g * NB + tid] = acc;
  }
  if (tid < 128) {
    float acc = br1[tid];
    const float4* wr = (const float4*)&Wr1[(size_t)tid * H];
    for (int k4 = 0; k4 < H / 4; k4++) {
      float4 wv = wr[k4];
      float4 av = *(const float4*)&zsh[k4 * 4];
      acc += av.x * wv.x + av.y * wv.y + av.z * wv.z + av.w * wv.w;
    }
    r1sh[tid] = fmaxf(acc, 0.f);
  }
  __syncthreads();
  if (tid < 64) {
    float s2 = r1sh[tid] * Wr2[tid] + r1sh[tid + 64] * Wr2[tid + 64];
    s2 = wave_reduce_sum(s2);
    if (tid == 0) out[(size_t)NGRAPH * NB + g] = tanhf(s2 + br2[0]);
  }
}

// ---------------- launcher ----------------
extern "C" void kernel_launch(void* const* d_in, const int* in_sizes, int n_in,
                              void* d_out, int out_size, void* d_ws, size_t ws_size,
                              hipStream_t stream) {
  const float* x_in   = (const float*)d_in[0];
  const int*   eidx   = (const int*)d_in[1];
  const int*   batch  = (const int*)d_in[2];
  const float* W_in   = (const float*)d_in[3];
  const float* b_in   = (const float*)d_in[4];
  const float* Wl     = (const float*)d_in[5];
  const float* bl     = (const float*)d_in[6];
  const float* Wr     = (const float*)d_in[7];
  const float* br     = (const float*)d_in[8];
  const float* att    = (const float*)d_in[9];
  const float* bias_c = (const float*)d_in[10];
  const float* ln_g   = (const float*)d_in[11];
  const float* ln_b   = (const float*)d_in[12];
  const float* Wg1    = (const float*)d_in[13];
  const float* bg1    = (const float*)d_in[14];
  const float* Wg2    = (const float*)d_in[15];
  const float* bg2    = (const float*)d_in[16];
  const float* Ws     = (const float*)d_in[17];
  const float* bs     = (const float*)d_in[18];
  const float* Wc     = (const float*)d_in[19];
  const float* bc     = (const float*)d_in[20];
  const float* Wr1    = (const float*)d_in[21];
  const float* br1    = (const float*)d_in[22];
  const float* Wr2    = (const float*)d_in[23];
  const float* br2    = (const float*)d_in[24];
  float* out = (float*)d_out;

  char* w = (char*)d_ws;
  u16* x_h    = (u16*)w;    w += sizeof(u16) * (size_t)N_NODES * H;
  u16* xl_h   = (u16*)w;    w += sizeof(u16) * (size_t)N_NODES * H;
  u16* xr_h   = (u16*)w;    w += sizeof(u16) * (size_t)N_NODES * H;
  u16* xin_h  = (u16*)w;    w += sizeof(u16) * (size_t)N_NODES * IN_DIM;
  u16* win_h  = (u16*)w;    w += sizeof(u16) * (size_t)H * IN_DIM;
  u16* wl_h   = (u16*)w;    w += sizeof(u16) * (size_t)LAYERS * H * H;
  u16* wr_h   = (u16*)w;    w += sizeof(u16) * (size_t)LAYERS * H * H;
  u16* wg1_h  = (u16*)w;    w += sizeof(u16) * (size_t)H * H;
  float* pooled = (float*)w; w += sizeof(float) * NGRAPH * H;
  float* gate = (float*)w;  w += sizeof(float) * N_NODES;
  float* gmax = (float*)w;  w += sizeof(float) * NGRAPH;
  float* gdinv= (float*)w;  w += sizeof(float) * NGRAPH;
  int* cnt    = (int*)w;    w += sizeof(int) * N_NODES;
  int* rowp   = (int*)w;    w += sizeof(int) * (N_NODES + 1);
  int* col    = (int*)w;    w += sizeof(int) * EE;
  int* partial= (int*)w;    w += sizeof(int) * N_NODES;
  int* bsums  = (int*)w;    w += sizeof(int) * 256;
  int* gstart = (int*)w;    w += sizeof(int) * NGRAPH;
  int* gend   = (int*)w;    w += sizeof(int) * NGRAPH;
  (void)ws_size; (void)n_in; (void)in_sizes; (void)out_size;

  const int* src = eidx;
  const int* dst = eidx + N_EDGES;
  int nblkN = (N_NODES + 255) / 256;
  int nblkE = (N_EDGES + 255) / 256;
  int mtiles = (N_NODES + GTM - 1) / GTM;
  int mtiles2 = (N_NODES + DTM - 1) / DTM;

  // CSR build (by dst, self-loops included)
  init_counts_kernel<<<nblkN, 256, 0, stream>>>(cnt);
  count_edges_kernel<<<nblkE, 256, 0, stream>>>(dst, cnt);
  scan_blocks_kernel<<<nblkN, 256, 0, stream>>>(cnt, partial, bsums, N_NODES);
  scan_sums_kernel<<<1, 256, 0, stream>>>(bsums, nblkN);
  scan_write_kernel<<<nblkN, 256, 0, stream>>>(partial, bsums, rowp, N_NODES);
  fill_self_kernel<<<nblkN, 256, 0, stream>>>(rowp, col, cnt);
  fill_edges_kernel<<<nblkE, 256, 0, stream>>>(src, dst, cnt, col);

  // casts
  {
    int maxn4 = LAYERS * H * H / 4;
    dim3 gcast((maxn4 + 255) / 256, 4);
    cast_weights_kernel<<<gcast, 256, 0, stream>>>(W_in, Wg1, Wl, Wr,
                                                   win_h, wg1_h, wl_h, wr_h);
    int n4 = N_NODES * IN_DIM / 4;
    cast_f16_kernel<<<(n4 + 255) / 256, 256, 0, stream>>>(x_in, xin_h, n4);
  }

  // input projection -> x_h
  dim3 gproj(2, mtiles);
  gemm_proj_kernel<<<gproj, 256, 0, stream>>>(xin_h, win_h, b_in, x_h, N_NODES, IN_DIM);

  int nblkV = N_NODES / 4;
  for (int l = 0; l < LAYERS; l++) {
    gemm_dual2_kernel<<<mtiles2, 256, 0, stream>>>(x_h,
        wl_h + (size_t)l * H * H, wr_h + (size_t)l * H * H,
        bl + l * H, br + l * H, xl_h, xr_h, N_NODES);
    layer_fused_kernel<<<nblkV, 256, 0, stream>>>(xl_h, xr_h, x_h, rowp, col,
        att + l * H, bias_c + l * H, ln_g + l * H, ln_b + l * H);
  }

  // gate (fused GEMM + row-dot)
  gate_init_kernel<<<nblkN, 256, 0, stream>>>(gate, bg2, gstart, gend);
  dim3 ggate(2, mtiles);
  gemm_gate_kernel<<<ggate, 256, 0, stream>>>(x_h, wg1_h, bg1, Wg2, gate, N_NODES);

  // pooling
  gbounds_kernel<<<nblkN, 256, 0, stream>>>(batch, gstart, gend);
  pool_prep_kernel<<<NGRAPH, 256, 0, stream>>>(gate, gstart, gend, gmax, gdinv, pooled);
  pool_accum_kernel<<<(N_NODES + 127) / 128, 256, 0, stream>>>(gate, x_h, batch, gmax, gdinv, pooled);

  // fused heads
  head_kernel<<<NGRAPH, 256, 0, stream>>>(pooled, Ws, bs, Wc, bc, Wr1, br1, Wr2, br2, out);
}

// Round 8
// 651.063 us; speedup vs baseline: 1.0035x; 1.0035x over previous
//
#include <hip/hip_runtime.h>
#include <math.h>

#define N_NODES 50000
#define N_EDGES 300000
#define IN_DIM 64
#define H 256
#define LAYERS 4
#define NB 181
#define NGRAPH 64
#define EE (N_EDGES + N_NODES)
#define NEG_SLOPE 0.2f
#define LN_EPS 1e-5f

typedef unsigned short u16;
typedef __attribute__((ext_vector_type(8))) _Float16 half8;
typedef __attribute__((ext_vector_type(2))) _Float16 half2v;
typedef __attribute__((ext_vector_type(4))) float floatx4;

__device__ __forceinline__ u16 f2h(float f) {
  _Float16 h = (_Float16)f;
  return __builtin_bit_cast(u16, h);
}
__device__ __forceinline__ float h2f(u16 b) {
  return (float)__builtin_bit_cast(_Float16, b);
}

__device__ __forceinline__ float wave_reduce_sum(float v) {
  #pragma unroll
  for (int off = 32; off > 0; off >>= 1) v += __shfl_xor(v, off, 64);
  return v;
}

// ---------------- casts ----------------
__global__ void cast_f16_kernel(const float* __restrict__ in, u16* __restrict__ out, int n4) {
  int i = blockIdx.x * 256 + threadIdx.x;
  if (i < n4) {
    float4 f = ((const float4*)in)[i];
    ushort4 o;
    o.x = f2h(f.x); o.y = f2h(f.y); o.z = f2h(f.z); o.w = f2h(f.w);
    ((ushort4*)out)[i] = o;
  }
}

__global__ void cast_weights_kernel(
    const float* __restrict__ W_in, const float* __restrict__ Wg1,
    const float* __restrict__ Wl, const float* __restrict__ Wr,
    u16* __restrict__ win_h, u16* __restrict__ wg1_h,
    u16* __restrict__ wl_h, u16* __restrict__ wr_h)
{
  int i = blockIdx.x * 256 + threadIdx.x;
  int which = blockIdx.y;
  const float* s; u16* dd; int n4;
  if (which == 0)      { s = W_in; dd = win_h; n4 = H * IN_DIM / 4; }
  else if (which == 1) { s = Wg1;  dd = wg1_h; n4 = H * H / 4; }
  else if (which == 2) { s = Wl;   dd = wl_h;  n4 = LAYERS * H * H / 4; }
  else                 { s = Wr;   dd = wr_h;  n4 = LAYERS * H * H / 4; }
  if (i < n4) {
    float4 f = ((const float4*)s)[i];
    ushort4 o;
    o.x = f2h(f.x); o.y = f2h(f.y); o.z = f2h(f.z); o.w = f2h(f.w);
    ((ushort4*)dd)[i] = o;
  }
}

// ---------------- CSR build ----------------
__global__ void init_counts_kernel(int* __restrict__ cnt) {
  int i = blockIdx.x * 256 + threadIdx.x;
  if (i < N_NODES) cnt[i] = 1;  // self loop
}

__global__ void count_edges_kernel(const int* __restrict__ dst, int* __restrict__ cnt) {
  int e = blockIdx.x * 256 + threadIdx.x;
  if (e < N_EDGES) atomicAdd(&cnt[dst[e]], 1);
}

__global__ void scan_blocks_kernel(const int* __restrict__ cnt, int* __restrict__ partial,
                                   int* __restrict__ bsums, int n) {
  __shared__ int buf[256];
  int tid = threadIdx.x;
  int i = blockIdx.x * 256 + tid;
  buf[tid] = (i < n) ? cnt[i] : 0;
  __syncthreads();
  #pragma unroll
  for (int off = 1; off < 256; off <<= 1) {
    int t = (tid >= off) ? buf[tid - off] : 0;
    __syncthreads();
    buf[tid] += t;
    __syncthreads();
  }
  if (i < n) partial[i] = buf[tid];
  if (tid == 255) bsums[blockIdx.x] = buf[255];
}

__global__ void scan_sums_kernel(int* __restrict__ bsums, int nblk) {
  __shared__ int buf[256];
  int tid = threadIdx.x;
  buf[tid] = (tid < nblk) ? bsums[tid] : 0;
  __syncthreads();
  #pragma unroll
  for (int off = 1; off < 256; off <<= 1) {
    int t = (tid >= off) ? buf[tid - off] : 0;
    __syncthreads();
    buf[tid] += t;
    __syncthreads();
  }
  if (tid < nblk) bsums[tid] = buf[tid];
}

__global__ void scan_write_kernel(const int* __restrict__ partial, const int* __restrict__ bsums,
                                  int* __restrict__ rowp, int n) {
  int i = blockIdx.x * 256 + threadIdx.x;
  if (i < n) {
    int b = blockIdx.x;
    int off = (b > 0) ? bsums[b - 1] : 0;
    rowp[i + 1] = partial[i] + off;
    if (i == 0) rowp[0] = 0;
  }
}

__global__ void fill_self_kernel(const int* __restrict__ rowp, int* __restrict__ col,
                                 int* __restrict__ fillpos) {
  int i = blockIdx.x * 256 + threadIdx.x;
  if (i < N_NODES) {
    int p = rowp[i];
    col[p] = i;
    fillpos[i] = p + 1;
  }
}

__global__ void fill_edges_kernel(const int* __restrict__ src, const int* __restrict__ dst,
                                  int* __restrict__ fillpos, int* __restrict__ col) {
  int e = blockIdx.x * 256 + threadIdx.x;
  if (e < N_EDGES) {
    int d = dst[e];
    int p = atomicAdd(&fillpos[d], 1);
    col[p] = src[e];
  }
}

// ---------------- MFMA GEMM tiles ----------------
#define GTM 128
#define GTK 64
#define LDB 72
#define SSTR 132

__global__ __launch_bounds__(256) void gemm_proj_kernel(
    const u16* __restrict__ A, const u16* __restrict__ W,
    const float* __restrict__ bias, u16* __restrict__ outh, int M, int K)
{
  __shared__ u16 smem[2 * GTM * LDB];
  u16* As = smem;
  u16* Bs = smem + GTM * LDB;
  int tid = threadIdx.x;
  int lane = tid & 63;
  int wave = tid >> 6;
  int wm = (wave >> 1) * 64;
  int wn = (wave & 1) * 64;
  int bm = blockIdx.y * GTM;
  int n0 = blockIdx.x * 128;
  int lr = tid >> 3;
  int lc = (tid & 7) * 8;

  floatx4 zero4 = {0.f, 0.f, 0.f, 0.f};
  floatx4 acc[4][4];
  #pragma unroll
  for (int i = 0; i < 4; i++)
    #pragma unroll
    for (int j = 0; j < 4; j++) acc[i][j] = zero4;

  int q8 = (lane >> 4) * 8;
  int mrow = lane & 15;

  for (int k0 = 0; k0 < K; k0 += GTK) {
    __syncthreads();
    #pragma unroll
    for (int p = 0; p < 4; p++) {
      int row = lr + p * 32;
      int gr = bm + row;
      uint4 av = {0, 0, 0, 0};
      if (gr < M) av = *(const uint4*)&A[(size_t)gr * K + k0 + lc];
      *(uint4*)&As[row * LDB + lc] = av;
      uint4 bv = *(const uint4*)&W[(size_t)(n0 + row) * K + k0 + lc];
      *(uint4*)&Bs[row * LDB + lc] = bv;
    }
    __syncthreads();
    #pragma unroll
    for (int h = 0; h < 2; h++) {
      half8 af[4], bf[4];
      #pragma unroll
      for (int i = 0; i < 4; i++)
        af[i] = *(const half8*)&As[(wm + i * 16 + mrow) * LDB + h * 32 + q8];
      #pragma unroll
      for (int j = 0; j < 4; j++)
        bf[j] = *(const half8*)&Bs[(wn + j * 16 + mrow) * LDB + h * 32 + q8];
      #pragma unroll
      for (int i = 0; i < 4; i++)
        #pragma unroll
        for (int j = 0; j < 4; j++)
          acc[i][j] = __builtin_amdgcn_mfma_f32_16x16x32_f16(af[i], bf[j], acc[i][j], 0, 0, 0);
    }
  }

  __syncthreads();
  u16* stage = smem;
  int ccol = lane & 15;
  int crow4 = (lane >> 4) * 4;
  #pragma unroll
  for (int j = 0; j < 4; j++) {
    float bv = bias[n0 + wn + j * 16 + ccol];
    #pragma unroll
    for (int i = 0; i < 4; i++) {
      #pragma unroll
      for (int r = 0; r < 4; r++) {
        int row = wm + i * 16 + crow4 + r;
        stage[row * SSTR + wn + j * 16 + ccol] = f2h(acc[i][j][r] + bv);
      }
    }
  }
  __syncthreads();
  int rr = tid >> 1;
  int c0 = (tid & 1) * 64;
  int grow = bm + rr;
  if (grow < M) {
    const ushort4* sp = (const ushort4*)&stage[rr * SSTR + c0];
    ushort4* gp = (ushort4*)&outh[(size_t)grow * H + n0 + c0];
    #pragma unroll
    for (int q = 0; q < 16; q++) gp[q] = sp[q];
  }
}

// ---------------- dual GEMM v2: A-resident in LDS, 64-row m-tiles ----------------
#define DTM 64
#define AST 264
#define SSTR2 132

__global__ __launch_bounds__(256) void gemm_dual2_kernel(
    const u16* __restrict__ A, const u16* __restrict__ Wlb, const u16* __restrict__ Wrb,
    const float* __restrict__ biasL, const float* __restrict__ biasR,
    u16* __restrict__ outL, u16* __restrict__ outR, int M)
{
  __shared__ u16 As[DTM * AST];
  __shared__ u16 Bs[128 * LDB];
  int tid = threadIdx.x;
  int lane = tid & 63;
  int wave = tid >> 6;
  int wn = wave * 32;
  int bm = blockIdx.x * DTM;
  int mrow = lane & 15;
  int q8 = (lane >> 4) * 8;
  int ccol = lane & 15;
  int crow4 = (lane >> 4) * 4;

  {
    int col = (tid & 31) * 8;
    int r0 = tid >> 5;
    #pragma unroll
    for (int it = 0; it < 8; it++) {
      int row = r0 + it * 8;
      int gr = bm + row;
      uint4 av = {0, 0, 0, 0};
      if (gr < M) av = *(const uint4*)&A[(size_t)gr * H + col];
      *(uint4*)&As[row * AST + col] = av;
    }
  }

  floatx4 zero4 = {0.f, 0.f, 0.f, 0.f};

  for (int nt = 0; nt < 4; nt++) {
    const u16* W = (nt < 2) ? Wlb : Wrb;
    const float* bias = (nt < 2) ? biasL : biasR;
    u16* outp = (nt < 2) ? outL : outR;
    int n0 = (nt & 1) * 128;

    floatx4 acc[4][2];
    #pragma unroll
    for (int i = 0; i < 4; i++) {
      acc[i][0] = zero4;
      acc[i][1] = zero4;
    }

    for (int k0 = 0; k0 < H; k0 += 64) {
      __syncthreads();
      {
        int col = (tid & 7) * 8;
        int r0 = tid >> 3;
        #pragma unroll
        for (int p2 = 0; p2 < 4; p2++) {
          int row = r0 + p2 * 32;
          uint4 bv = *(const uint4*)&W[(size_t)(n0 + row) * H + k0 + col];
          *(uint4*)&Bs[row * LDB + col] = bv;
        }
      }
      __syncthreads();
      #pragma unroll
      for (int h = 0; h < 2; h++) {
        half8 af[4], bf[2];
        #pragma unroll
        for (int i = 0; i < 4; i++)
          af[i] = *(const half8*)&As[(i * 16 + mrow) * AST + k0 + h * 32 + q8];
        #pragma unroll
        for (int j = 0; j < 2; j++)
          bf[j] = *(const half8*)&Bs[(wn + j * 16 + mrow) * LDB + h * 32 + q8];
        #pragma unroll
        for (int i = 0; i < 4; i++)
          #pragma unroll
          for (int j = 0; j < 2; j++)
            acc[i][j] = __builtin_amdgcn_mfma_f32_16x16x32_f16(af[i], bf[j], acc[i][j], 0, 0, 0);
      }
    }

    __syncthreads();
    u16* stage = Bs;
    #pragma unroll
    for (int j = 0; j < 2; j++) {
      float bv = bias[n0 + wn + j * 16 + ccol];
      #pragma unroll
      for (int i = 0; i < 4; i++) {
        #pragma unroll
        for (int r = 0; r < 4; r++) {
          int row = i * 16 + crow4 + r;
          stage[row * SSTR2 + wn + j * 16 + ccol] = f2h(acc[i][j][r] + bv);
        }
      }
    }
    __syncthreads();
    {
      int row = tid >> 2;
      int c0 = (tid & 3) * 32;
      int grow = bm + row;
      if (grow < M) {
        #pragma unroll
        for (int q = 0; q < 8; q++)
          *(ushort4*)&outp[(size_t)grow * H + n0 + c0 + q * 4] =
              *(const ushort4*)&stage[row * SSTR2 + c0 + q * 4];
      }
    }
  }
}

// gate GEMM: gate[row] += sum_col relu(x@Wg1 + bg1)[col] * Wg2[col]; gate pre-init to bg2
__global__ __launch_bounds__(256) void gemm_gate_kernel(
    const u16* __restrict__ A, const u16* __restrict__ W,
    const float* __restrict__ bias, const float* __restrict__ Wg2,
    float* __restrict__ gate, int M)
{
  __shared__ u16 smem[2 * GTM * LDB];
  u16* As = smem;
  u16* Bs = smem + GTM * LDB;
  int tid = threadIdx.x;
  int lane = tid & 63;
  int wave = tid >> 6;
  int wm = (wave >> 1) * 64;
  int wn = (wave & 1) * 64;
  int bm = blockIdx.y * GTM;
  int bn = blockIdx.x * 128;
  int lr = tid >> 3;
  int lc = (tid & 7) * 8;

  floatx4 zero4 = {0.f, 0.f, 0.f, 0.f};
  floatx4 acc[4][4];
  #pragma unroll
  for (int i = 0; i < 4; i++)
    #pragma unroll
    for (int j = 0; j < 4; j++) acc[i][j] = zero4;

  int q8 = (lane >> 4) * 8;
  int mrow = lane & 15;

  for (int k0 = 0; k0 < H; k0 += GTK) {
    __syncthreads();
    #pragma unroll
    for (int p = 0; p < 4; p++) {
      int row = lr + p * 32;
      int gr = bm + row;
      uint4 av = {0, 0, 0, 0};
      if (gr < M) av = *(const uint4*)&A[(size_t)gr * H + k0 + lc];
      *(uint4*)&As[row * LDB + lc] = av;
      uint4 bv = *(const uint4*)&W[(size_t)(bn + row) * H + k0 + lc];
      *(uint4*)&Bs[row * LDB + lc] = bv;
    }
    __syncthreads();
    #pragma unroll
    for (int h = 0; h < 2; h++) {
      half8 af[4], bf[4];
      #pragma unroll
      for (int i = 0; i < 4; i++)
        af[i] = *(const half8*)&As[(wm + i * 16 + mrow) * LDB + h * 32 + q8];
      #pragma unroll
      for (int j = 0; j < 4; j++)
        bf[j] = *(const half8*)&Bs[(wn + j * 16 + mrow) * LDB + h * 32 + q8];
      #pragma unroll
      for (int i = 0; i < 4; i++)
        #pragma unroll
        for (int j = 0; j < 4; j++)
          acc[i][j] = __builtin_amdgcn_mfma_f32_16x16x32_f16(af[i], bf[j], acc[i][j], 0, 0, 0);
    }
  }

  int ccol = lane & 15;
  float bv[4], wv[4];
  #pragma unroll
  for (int j = 0; j < 4; j++) {
    int col = bn + wn + j * 16 + ccol;
    bv[j] = bias[col];
    wv[j] = Wg2[col];
  }
  #pragma unroll
  for (int i = 0; i < 4; i++) {
    #pragma unroll
    for (int r = 0; r < 4; r++) {
      float p = 0.f;
      #pragma unroll
      for (int j = 0; j < 4; j++) {
        float hcol = fmaxf(acc[i][j][r] + bv[j], 0.f);
        p += hcol * wv[j];
      }
      p += __shfl_xor(p, 1, 64);
      p += __shfl_xor(p, 2, 64);
      p += __shfl_xor(p, 4, 64);
      p += __shfl_xor(p, 8, 64);
      int row = bm + wm + i * 16 + (lane >> 4) * 4 + r;
      if ((lane & 15) == 0 && row < M) atomicAdd(&gate[row], p);
    }
  }
}

// ---------------- fused edge softmax + aggregate + LN + residual ----------------
// R6 structure (1 node/wave, 64 lanes x 4 feats, unroll-2) + packed fp16 math.
__global__ __launch_bounds__(256) void layer_fused_kernel(
    const u16* __restrict__ xl, const u16* __restrict__ xr,
    u16* __restrict__ xst,
    const int* __restrict__ rowp, const int* __restrict__ col,
    const float* __restrict__ att, const float* __restrict__ bias_c,
    const float* __restrict__ ln_g, const float* __restrict__ ln_b)
{
  int lane = threadIdx.x & 63;
  int v = blockIdx.x * 4 + (threadIdx.x >> 6);
  if (v >= N_NODES) return;
  int f4 = lane << 2;
  size_t rowbase = (size_t)v * H;

  uint2 xrq = *(const uint2*)&xr[rowbase + f4];
  half2v xrh[2] = {__builtin_bit_cast(half2v, xrq.x), __builtin_bit_cast(half2v, xrq.y)};
  float4 attv = *(const float4*)&att[f4];
  half2v ath[2] = {{(_Float16)attv.x, (_Float16)attv.y},
                   {(_Float16)attv.z, (_Float16)attv.w}};
  const half2v kslope = {(_Float16)NEG_SLOPE, (_Float16)NEG_SLOPE};

  int beg = rowp[v], end = rowp[v + 1];
  float m = -INFINITY, d = 0.f;
  half2v o0 = {(_Float16)0.f, (_Float16)0.f};
  half2v o1 = {(_Float16)0.f, (_Float16)0.f};

  for (int p = beg; p < end; p += 2) {
    int valid1 = (p + 1 < end);
    int u0 = col[p];
    int u1 = valid1 ? col[p + 1] : u0;
    uint2 aq0 = *(const uint2*)&xl[(size_t)u0 * H + f4];
    uint2 aq1 = *(const uint2*)&xl[(size_t)u1 * H + f4];
    half2v a00 = __builtin_bit_cast(half2v, aq0.x);
    half2v a01 = __builtin_bit_cast(half2v, aq0.y);
    half2v a10 = __builtin_bit_cast(half2v, aq1.x);
    half2v a11 = __builtin_bit_cast(half2v, aq1.y);
    half2v h00 = a00 + xrh[0], h01 = a01 + xrh[1];
    half2v h10 = a10 + xrh[0], h11 = a11 + xrh[1];
    half2v l00 = __builtin_elementwise_max(h00, h00 * kslope);
    half2v l01 = __builtin_elementwise_max(h01, h01 * kslope);
    half2v l10 = __builtin_elementwise_max(h10, h10 * kslope);
    half2v l11 = __builtin_elementwise_max(h11, h11 * kslope);
#if __has_builtin(__builtin_amdgcn_fdot2)
    float pe0 = __builtin_amdgcn_fdot2(l01, ath[1],
                 __builtin_amdgcn_fdot2(l00, ath[0], 0.f, false), false);
    float pe1 = __builtin_amdgcn_fdot2(l11, ath[1],
                 __builtin_amdgcn_fdot2(l10, ath[0], 0.f, false), false);
#else
    float pe0 = (float)l00[0] * (float)ath[0][0] + (float)l00[1] * (float)ath[0][1]
              + (float)l01[0] * (float)ath[1][0] + (float)l01[1] * (float)ath[1][1];
    float pe1 = (float)l10[0] * (float)ath[0][0] + (float)l10[1] * (float)ath[0][1]
              + (float)l11[0] * (float)ath[1][0] + (float)l11[1] * (float)ath[1][1];
#endif
    #pragma unroll
    for (int off = 32; off > 0; off >>= 1) {
      pe0 += __shfl_xor(pe0, off, 64);
      pe1 += __shfl_xor(pe1, off, 64);
    }
    if (!valid1) pe1 = -INFINITY;
    float mn = fmaxf(m, fmaxf(pe0, pe1));
    float sc = __expf(m - mn);    // exp(-inf)=0 first iteration
    float w0 = __expf(pe0 - mn);
    float w1 = __expf(pe1 - mn);  // 0 when invalid
    d = fmaf(d, sc, w0 + w1);
    _Float16 sch = (_Float16)sc, w0h = (_Float16)w0, w1h = (_Float16)w1;
    half2v scp = {sch, sch}, w0p = {w0h, w0h}, w1p = {w1h, w1h};
    half2v t0 = a00 * w0p + a10 * w1p;
    half2v t1 = a01 * w0p + a11 * w1p;
    o0 = o0 * scp + t0;
    o1 = o1 * scp + t1;
    m = mn;
  }

  float invd = 1.0f / d;
  float4 bc4 = *(const float4*)&bias_c[f4];
  float ox = fmaf((float)o0[0], invd, bc4.x);
  float oy = fmaf((float)o0[1], invd, bc4.y);
  float oz = fmaf((float)o1[0], invd, bc4.z);
  float ow = fmaf((float)o1[1], invd, bc4.w);
  float s = wave_reduce_sum(ox + oy + oz + ow);
  float mean = s * (1.0f / H);
  float cx = ox - mean, cy = oy - mean, cz = oz - mean, cw = ow - mean;
  float sq = wave_reduce_sum(cx * cx + cy * cy + cz * cz + cw * cw);
  float rstd = rsqrtf(sq * (1.0f / H) + LN_EPS);
  float4 g4 = *(const float4*)&ln_g[f4];
  float4 b4 = *(const float4*)&ln_b[f4];
  uint2 resq = *(const uint2*)&xst[rowbase + f4];
  half2v r0 = __builtin_bit_cast(half2v, resq.x);
  half2v r1 = __builtin_bit_cast(half2v, resq.y);
  float yx = fmaxf(fmaf(cx * rstd, g4.x, b4.x), 0.f) + (float)r0[0];
  float yy = fmaxf(fmaf(cy * rstd, g4.y, b4.y), 0.f) + (float)r0[1];
  float yz = fmaxf(fmaf(cz * rstd, g4.z, b4.z), 0.f) + (float)r1[0];
  float yw = fmaxf(fmaf(cw * rstd, g4.w, b4.w), 0.f) + (float)r1[1];
  ushort4 yb;
  yb.x = f2h(yx); yb.y = f2h(yy); yb.z = f2h(yz); yb.w = f2h(yw);
  *(ushort4*)&xst[rowbase + f4] = yb;
}

// ---------------- gate init (+ graph-bounds defaults) ----------------
__global__ void gate_init_kernel(float* __restrict__ gate, const float* __restrict__ bg2,
                                 int* __restrict__ gstart, int* __restrict__ gend) {
  int i = blockIdx.x * 256 + threadIdx.x;
  if (i < N_NODES) gate[i] = bg2[0];
  if (i < NGRAPH) { gstart[i] = 0; gend[i] = 0; }
}

// ---------------- graph bounds (sorted batch) ----------------
__global__ void gbounds_kernel(const int* __restrict__ batch, int* __restrict__ gstart,
                               int* __restrict__ gend) {
  int i = blockIdx.x * 256 + threadIdx.x;
  if (i < N_NODES) {
    int b = batch[i];
    if (i == 0 || batch[i - 1] != b) gstart[b] = i;
    if (i == N_NODES - 1 || batch[i + 1] != b) gend[b] = i + 1;
  }
}

// ---------------- pooling: per-graph softmax stats (+ pooled zero) ----------------
__global__ __launch_bounds__(256) void pool_prep_kernel(
    const float* __restrict__ gate, const int* __restrict__ gstart,
    const int* __restrict__ gend, float* __restrict__ gmax, float* __restrict__ gdinv,
    float* __restrict__ pooled)
{
  __shared__ float red[256];
  int g = blockIdx.x, tid = threadIdx.x;
  pooled[(size_t)g * H + tid] = 0.f;
  int s = gstart[g], e = gend[g];
  float lm = -INFINITY;
  for (int i = s + tid; i < e; i += 256) lm = fmaxf(lm, gate[i]);
  red[tid] = lm;
  __syncthreads();
  for (int off = 128; off; off >>= 1) {
    if (tid < off) red[tid] = fmaxf(red[tid], red[tid + off]);
    __syncthreads();
  }
  float m = red[0];
  __syncthreads();
  float lsum = 0.0f;
  for (int i = s + tid; i < e; i += 256) lsum += __expf(gate[i] - m);
  red[tid] = lsum;
  __syncthreads();
  for (int off = 128; off; off >>= 1) {
    if (tid < off) red[tid] += red[tid + off];
    __syncthreads();
  }
  if (tid == 0) {
    gmax[g] = m;
    gdinv[g] = (s < e) ? 1.0f / red[0] : 0.0f;
  }
}

// ---------------- pooling: weighted accumulate (128 nodes per block, fp16 x) ----------------
__global__ __launch_bounds__(256) void pool_accum_kernel(
    const float* __restrict__ gate, const u16* __restrict__ xh,
    const int* __restrict__ batch, const float* __restrict__ gmax,
    const float* __restrict__ gdinv, float* __restrict__ pooled)
{
  __shared__ float wl[128];
  __shared__ int gl[128];
  int b0 = blockIdx.x * 128;
  int tid = threadIdx.x;
  if (tid < 128) {
    int v = b0 + tid;
    if (v < N_NODES) {
      int g = batch[v];
      gl[tid] = g;
      wl[tid] = __expf(gate[v] - gmax[g]) * gdinv[g];
    } else {
      gl[tid] = -1;
      wl[tid] = 0.f;
    }
  }
  __syncthreads();
  int cnt = min(128, N_NODES - b0);
  float acc = 0.f;
  int cur = gl[0];
  for (int j = 0; j < cnt; j++) {
    int g = gl[j];
    if (g != cur) {
      atomicAdd(&pooled[(size_t)cur * H + tid], acc);
      acc = 0.f;
      cur = g;
    }
    acc += wl[j] * h2f(xh[(size_t)(b0 + j) * H + tid]);
  }
  if (cur >= 0) atomicAdd(&pooled[(size_t)cur * H + tid], acc);
}

// ---------------- fused head: pooled -> z -> {cls, r1} -> residual ----------------
__global__ __launch_bounds__(256) void head_kernel(
    const float* __restrict__ pooled,
    const float* __restrict__ Ws, const float* __restrict__ bs,
    const float* __restrict__ Wc, const float* __restrict__ bc,
    const float* __restrict__ Wr1, const float* __restrict__ br1,
    const float* __restrict__ Wr2, const float* __restrict__ br2,
    float* __restrict__ out)
{
  __shared__ float psh[256];
  __shared__ float zsh[256];
  __shared__ float r1sh[128];
  int g = blockIdx.x, tid = threadIdx.x;
  psh[tid] = pooled[(size_t)g * H + tid];
  __syncthreads();
  {
    float acc = bs[tid];
    const float4* wr = (const float4*)&Ws[(size_t)tid * H];
    for (int k4 = 0; k4 < H / 4; k4++) {
      float4 wv = wr[k4];
      float4 av = *(const float4*)&psh[k4 * 4];
      acc += av.x * wv.x + av.y * wv.y + av.z * wv.z + av.w * wv.w;
    }
    zsh[tid] = fmaxf(acc, 0.f);
  }
  __syncthreads();
  if (tid < NB) {
    float acc = bc[tid];
    const float4* wr = (const float4*)&Wc[(size_t)tid * H];
    for (int k4 = 0; k4 < H / 4; k4++) {
      float4 wv = wr[k4];
      float4 av = *(const float4*)&zsh[k4 * 4];
      acc += av.x * wv.x + av.y * wv.y + av.z * wv.z + av.w * wv.w;
    }
    out[(size_t)g * NB + tid] = acc;
  }
  if (tid < 128) {
    float acc = br1[tid];
    const float4* wr = (const float4*)&Wr1[(size_t)tid * H];
    for (int k4 = 0; k4 < H / 4; k4++) {
      float4 wv = wr[k4];
      float4 av = *(const float4*)&zsh[k4 * 4];
      acc += av.x * wv.x + av.y * wv.y + av.z * wv.z + av.w * wv.w;
    }
    r1sh[tid] = fmaxf(acc, 0.f);
  }
  __syncthreads();
  if (tid < 64) {
    float s2 = r1sh[tid] * Wr2[tid] + r1sh[tid + 64] * Wr2[tid + 64];
    s2 = wave_reduce_sum(s2);
    if (tid == 0) out[(size_t)NGRAPH * NB + g] = tanhf(s2 + br2[0]);
  }
}

// ---------------- launcher ----------------
extern "C" void kernel_launch(void* const* d_in, const int* in_sizes, int n_in,
                              void* d_out, int out_size, void* d_ws, size_t ws_size,
                              hipStream_t stream) {
  const float* x_in   = (const float*)d_in[0];
  const int*   eidx   = (const int*)d_in[1];
  const int*   batch  = (const int*)d_in[2];
  const float* W_in   = (const float*)d_in[3];
  const float* b_in   = (const float*)d_in[4];
  const float* Wl     = (const float*)d_in[5];
  const float* bl     = (const float*)d_in[6];
  const float* Wr     = (const float*)d_in[7];
  const float* br     = (const float*)d_in[8];
  const float* att    = (const float*)d_in[9];
  const float* bias_c = (const float*)d_in[10];
  const float* ln_g   = (const float*)d_in[11];
  const float* ln_b   = (const float*)d_in[12];
  const float* Wg1    = (const float*)d_in[13];
  const float* bg1    = (const float*)d_in[14];
  const float* Wg2    = (const float*)d_in[15];
  const float* bg2    = (const float*)d_in[16];
  const float* Ws     = (const float*)d_in[17];
  const float* bs     = (const float*)d_in[18];
  const float* Wc     = (const float*)d_in[19];
  const float* bc     = (const float*)d_in[20];
  const float* Wr1    = (const float*)d_in[21];
  const float* br1    = (const float*)d_in[22];
  const float* Wr2    = (const float*)d_in[23];
  const float* br2    = (const float*)d_in[24];
  float* out = (float*)d_out;

  char* w = (char*)d_ws;
  u16* x_h    = (u16*)w;    w += sizeof(u16) * (size_t)N_NODES * H;
  u16* xl_h   = (u16*)w;    w += sizeof(u16) * (size_t)N_NODES * H;
  u16* xr_h   = (u16*)w;    w += sizeof(u16) * (size_t)N_NODES * H;
  u16* xin_h  = (u16*)w;    w += sizeof(u16) * (size_t)N_NODES * IN_DIM;
  u16* win_h  = (u16*)w;    w += sizeof(u16) * (size_t)H * IN_DIM;
  u16* wl_h   = (u16*)w;    w += sizeof(u16) * (size_t)LAYERS * H * H;
  u16* wr_h   = (u16*)w;    w += sizeof(u16) * (size_t)LAYERS * H * H;
  u16* wg1_h  = (u16*)w;    w += sizeof(u16) * (size_t)H * H;
  float* pooled = (float*)w; w += sizeof(float) * NGRAPH * H;
  float* gate = (float*)w;  w += sizeof(float) * N_NODES;
  float* gmax = (float*)w;  w += sizeof(float) * NGRAPH;
  float* gdinv= (float*)w;  w += sizeof(float) * NGRAPH;
  int* cnt    = (int*)w;    w += sizeof(int) * N_NODES;
  int* rowp   = (int*)w;    w += sizeof(int) * (N_NODES + 1);
  int* col    = (int*)w;    w += sizeof(int) * EE;
  int* partial= (int*)w;    w += sizeof(int) * N_NODES;
  int* bsums  = (int*)w;    w += sizeof(int) * 256;
  int* gstart = (int*)w;    w += sizeof(int) * NGRAPH;
  int* gend   = (int*)w;    w += sizeof(int) * NGRAPH;
  (void)ws_size; (void)n_in; (void)in_sizes; (void)out_size;

  const int* src = eidx;
  const int* dst = eidx + N_EDGES;
  int nblkN = (N_NODES + 255) / 256;
  int nblkE = (N_EDGES + 255) / 256;
  int mtiles = (N_NODES + GTM - 1) / GTM;
  int mtiles2 = (N_NODES + DTM - 1) / DTM;

  // CSR build (by dst, self-loops included)
  init_counts_kernel<<<nblkN, 256, 0, stream>>>(cnt);
  count_edges_kernel<<<nblkE, 256, 0, stream>>>(dst, cnt);
  scan_blocks_kernel<<<nblkN, 256, 0, stream>>>(cnt, partial, bsums, N_NODES);
  scan_sums_kernel<<<1, 256, 0, stream>>>(bsums, nblkN);
  scan_write_kernel<<<nblkN, 256, 0, stream>>>(partial, bsums, rowp, N_NODES);
  fill_self_kernel<<<nblkN, 256, 0, stream>>>(rowp, col, cnt);
  fill_edges_kernel<<<nblkE, 256, 0, stream>>>(src, dst, cnt, col);

  // casts
  {
    int maxn4 = LAYERS * H * H / 4;
    dim3 gcast((maxn4 + 255) / 256, 4);
    cast_weights_kernel<<<gcast, 256, 0, stream>>>(W_in, Wg1, Wl, Wr,
                                                   win_h, wg1_h, wl_h, wr_h);
    int n4 = N_NODES * IN_DIM / 4;
    cast_f16_kernel<<<(n4 + 255) / 256, 256, 0, stream>>>(x_in, xin_h, n4);
  }

  // input projection -> x_h
  dim3 gproj(2, mtiles);
  gemm_proj_kernel<<<gproj, 256, 0, stream>>>(xin_h, win_h, b_in, x_h, N_NODES, IN_DIM);

  int nblkV = N_NODES / 4;
  for (int l = 0; l < LAYERS; l++) {
    gemm_dual2_kernel<<<mtiles2, 256, 0, stream>>>(x_h,
        wl_h + (size_t)l * H * H, wr_h + (size_t)l * H * H,
        bl + l * H, br + l * H, xl_h, xr_h, N_NODES);
    layer_fused_kernel<<<nblkV, 256, 0, stream>>>(xl_h, xr_h, x_h, rowp, col,
        att + l * H, bias_c + l * H, ln_g + l * H, ln_b + l * H);
  }

  // gate (fused GEMM + row-dot)
  gate_init_kernel<<<nblkN, 256, 0, stream>>>(gate, bg2, gstart, gend);
  dim3 ggate(2, mtiles);
  gemm_gate_kernel<<<ggate, 256, 0, stream>>>(x_h, wg1_h, bg1, Wg2, gate, N_NODES);

  // pooling
  gbounds_kernel<<<nblkN, 256, 0, stream>>>(batch, gstart, gend);
  pool_prep_kernel<<<NGRAPH, 256, 0, stream>>>(gate, gstart, gend, gmax, gdinv, pooled);
  pool_accum_kernel<<<(N_NODES + 127) / 128, 256, 0, stream>>>(gate, x_h, batch, gmax, gdinv, pooled);

  // fused heads
  head_kernel<<<NGRAPH, 256, 0, stream>>>(pooled, Ws, bs, Wc, bc, Wr1, br1, Wr2, br2, out);
}